// Round 1
// baseline (16721.216 us; speedup 1.0000x reference)
//
#include <hip/hip_runtime.h>

// PopulationODE: sequential RK4 scan, T=4096, state=4, HID=32.
// One wave64 does the whole integration in registers.
// Lane l: half = l>>5 splits each 32-dot into j=0..15 / j=16..31.

__device__ __forceinline__ float bperm(int addr, float v) {
  return __int_as_float(__builtin_amdgcn_ds_bpermute(addr, __float_as_int(v)));
}
__device__ __forceinline__ float rdlane(float v, int lane) {
  return __int_as_float(__builtin_amdgcn_readlane(__float_as_int(v), lane));
}
__device__ __forceinline__ float fexp2(float x) { return __builtin_amdgcn_exp2f(x); }
__device__ __forceinline__ float frcp(float x) { return __builtin_amdgcn_rcpf(x); }
// tanh(a) = 1 - 2/(exp2(2*log2e*a)+1); saturates correctly at +/-inf exp2.
__device__ __forceinline__ float ftanh(float a) {
  float e = fexp2(a * 2.8853900817779268f);
  return 1.0f - 2.0f * frcp(e + 1.0f);
}
// sigmoid(a) = 1/(1+exp2(-log2e*a))
__device__ __forceinline__ float fsigm(float a) {
  float e = fexp2(a * -1.4426950408889634f);
  return frcp(1.0f + e);
}

// 32x32 matvec, half-split across wave halves.
// W: per-lane 16 weights W[r][half*16+k]; BZ: bias (lower half) or 0 (upper);
// XIN: x replicated in both halves (lane l holds x[l&31]); RES: y[r] replicated.
#define MATVEC(W, BZ, XIN, RES) do {                                   \
    float a0_ = (BZ), a1_ = 0.0f;                                      \
    _Pragma("unroll")                                                  \
    for (int k_ = 0; k_ < 16; k_ += 2) {                               \
      a0_ = fmaf(W[k_],     bperm(addr[k_],     XIN), a0_);            \
      a1_ = fmaf(W[k_ + 1], bperm(addr[k_ + 1], XIN), a1_);            \
    }                                                                  \
    float s_ = a0_ + a1_;                                              \
    RES = s_ + bperm(aswap, s_);                                       \
  } while (0)

// One evaluation of f(y, s) -> k (4 uniform scalars)
#define FEVAL(YA, YB, YC, YD, SV, K0, K1, K2, K3) do {                 \
    float z_ = fmaf(winy0, (YA), binr);                                \
    z_ = fmaf(winy1, (YB), z_);                                        \
    z_ = fmaf(winy2, (YC), z_);                                        \
    z_ = fmaf(winy3, (YD), z_);                                        \
    z_ = fmaf(wins,  (SV), z_);                                        \
    float x_ = ftanh(z_);                                              \
    float u1_; MATVEC(w1a, bz1a, x_, u1_);                             \
    float t1_ = ftanh(u1_);                                            \
    float v1_; MATVEC(w1b, bz1b, t1_, v1_);                            \
    float x2_ = x_ + v1_;                                              \
    float u2_; MATVEC(w2a, bz2a, x2_, u2_);                            \
    float t2_ = ftanh(u2_);                                            \
    float v2_; MATVEC(w2b, bz2b, t2_, v2_);                            \
    float x3_ = x2_ + v2_;                                             \
    /* output head: 16-lane group g = lane>>4 computes Wout row g */   \
    float p_ = fmaf(woA, bperm(aw1, x3_), woB * bperm(aw2, x3_));      \
    p_ += __shfl_xor(p_, 1, 64);                                       \
    p_ += __shfl_xor(p_, 2, 64);                                       \
    p_ += __shfl_xor(p_, 4, 64);                                       \
    p_ += __shfl_xor(p_, 8, 64);                                       \
    float n0_ = fsigm(rdlane(p_, 0)  + bo0);                           \
    float n1_ = fsigm(rdlane(p_, 16) + bo1);                           \
    float n2_ = fsigm(rdlane(p_, 32) + bo2);                           \
    float n3_ = fsigm(rdlane(p_, 48) + bo3);                           \
    float s0_ = fsigm(YA), s1_ = fsigm(YB);                            \
    float s2_ = fsigm(YC), s3_ = fsigm(YD);                            \
    K0 = 0.01f * s0_ * (A0 - s0_) * n0_;                               \
    K1 = 0.01f * s1_ * (A1 - s1_) * n1_;                               \
    K2 = 0.01f * s2_ * (A2 - s2_) * n2_;                               \
    K3 = 0.01f * s3_ * (A3 - s3_) * n3_;                               \
  } while (0)

__global__ __launch_bounds__(64)
void ode_kernel(const float* __restrict__ s_grid,
                const float* __restrict__ y0in,
                const float* __restrict__ Win,
                const float* __restrict__ bin_,
                const float* __restrict__ W1a, const float* __restrict__ b1a,
                const float* __restrict__ W1b, const float* __restrict__ b1b,
                const float* __restrict__ W2a, const float* __restrict__ b2a,
                const float* __restrict__ W2b, const float* __restrict__ b2b,
                const float* __restrict__ Wout, const float* __restrict__ bout,
                const float* __restrict__ Aarr,
                float* __restrict__ out, int T) {
  const int lane = threadIdx.x;   // 0..63
  const int half = lane >> 5;     // which j-half of dot products
  const int r = lane & 31;        // hidden row owned by this lane

  // ---- load constants into registers (one-time) ----
  float w1a[16], w1b[16], w2a[16], w2b[16];
#pragma unroll
  for (int k = 0; k < 16; ++k) {
    w1a[k] = W1a[r * 32 + half * 16 + k];
    w1b[k] = W1b[r * 32 + half * 16 + k];
    w2a[k] = W2a[r * 32 + half * 16 + k];
    w2b[k] = W2b[r * 32 + half * 16 + k];
  }
  float winy0 = Win[r * 5 + 0], winy1 = Win[r * 5 + 1];
  float winy2 = Win[r * 5 + 2], winy3 = Win[r * 5 + 3];
  float wins = Win[r * 5 + 4];
  float binr = bin_[r];
  float bz1a = half ? 0.0f : b1a[r];
  float bz1b = half ? 0.0f : b1b[r];
  float bz2a = half ? 0.0f : b2a[r];
  float bz2b = half ? 0.0f : b2b[r];

  const int g = lane >> 4;     // Wout row handled by this 16-lane group
  const int j16 = lane & 15;
  float woA = Wout[g * 32 + j16];
  float woB = Wout[g * 32 + j16 + 16];
  float bo0 = bout[0], bo1 = bout[1], bo2 = bout[2], bo3 = bout[3];
  float A0 = Aarr[0], A1 = Aarr[1], A2 = Aarr[2], A3 = Aarr[3];

  // bpermute byte-address tables (constant for whole kernel)
  int addr[16];
  const int hb = (lane & 32) * 2;  // half*64 bytes
#pragma unroll
  for (int k = 0; k < 16; ++k) addr[k] = hb + 4 * k;
  const int aswap = ((lane + 32) & 63) * 4;
  const int aw1 = 4 * j16, aw2 = 4 * (j16 + 16);

  // ---- state (uniform across lanes) ----
  float y0v = y0in[0], y1v = y0in[1], y2v = y0in[2], y3v = y0in[3];

  if (lane < 4) {
    float ov = (lane == 0) ? y0v : (lane == 1) ? y1v : (lane == 2) ? y2v : y3v;
    out[lane] = ov;
  }

  float sp = s_grid[0];
  float sn = s_grid[1];

  for (int t = 0; t < T - 1; ++t) {
    // prefetch s for next iteration (latency hidden under this step)
    float snn = s_grid[(t + 2 < T) ? (t + 2) : (T - 1)];
    float h = sn - sp;

    float k10, k11, k12, k13, k20, k21, k22, k23;
    float k30, k31, k32, k33, k40, k41, k42, k43;

    FEVAL(y0v, y1v, y2v, y3v, sp, k10, k11, k12, k13);

    float hh = 0.5f * h;
    float ya0 = fmaf(hh, k10, y0v), ya1 = fmaf(hh, k11, y1v);
    float ya2 = fmaf(hh, k12, y2v), ya3 = fmaf(hh, k13, y3v);
    FEVAL(ya0, ya1, ya2, ya3, sp, k20, k21, k22, k23);

    float yb0 = fmaf(hh, k20, y0v), yb1 = fmaf(hh, k21, y1v);
    float yb2 = fmaf(hh, k22, y2v), yb3 = fmaf(hh, k23, y3v);
    FEVAL(yb0, yb1, yb2, yb3, sp, k30, k31, k32, k33);

    float yc0 = fmaf(h, k30, y0v), yc1 = fmaf(h, k31, y1v);
    float yc2 = fmaf(h, k32, y2v), yc3 = fmaf(h, k33, y3v);
    FEVAL(yc0, yc1, yc2, yc3, sp, k40, k41, k42, k43);

    float h6 = h * (1.0f / 6.0f);
    y0v = fmaf(h6, k10 + k40 + 2.0f * (k20 + k30), y0v);
    y1v = fmaf(h6, k11 + k41 + 2.0f * (k21 + k31), y1v);
    y2v = fmaf(h6, k12 + k42 + 2.0f * (k22 + k32), y2v);
    y3v = fmaf(h6, k13 + k43 + 2.0f * (k23 + k33), y3v);

    if (lane < 4) {
      float ov = (lane == 0) ? y0v : (lane == 1) ? y1v : (lane == 2) ? y2v : y3v;
      out[(size_t)(t + 1) * 4 + lane] = ov;
    }

    sp = sn;
    sn = snn;
  }
}

extern "C" void kernel_launch(void* const* d_in, const int* in_sizes, int n_in,
                              void* d_out, int out_size, void* d_ws, size_t ws_size,
                              hipStream_t stream) {
  const float* s_grid = (const float*)d_in[0];
  const float* y0 = (const float*)d_in[1];
  const float* Win = (const float*)d_in[2];
  const float* bin_ = (const float*)d_in[3];
  const float* W1a = (const float*)d_in[4];
  const float* b1a = (const float*)d_in[5];
  const float* W1b = (const float*)d_in[6];
  const float* b1b = (const float*)d_in[7];
  const float* W2a = (const float*)d_in[8];
  const float* b2a = (const float*)d_in[9];
  const float* W2b = (const float*)d_in[10];
  const float* b2b = (const float*)d_in[11];
  const float* Wout = (const float*)d_in[12];
  const float* bout = (const float*)d_in[13];
  const float* A = (const float*)d_in[14];
  int T = in_sizes[0];

  ode_kernel<<<1, 64, 0, stream>>>(s_grid, y0, Win, bin_, W1a, b1a, W1b, b1b,
                                   W2a, b2a, W2b, b2b, Wout, bout, A,
                                   (float*)d_out, T);
}

// Round 2
// 10444.911 us; speedup vs baseline: 1.6009x; 1.6009x over previous
//
#include <hip/hip_runtime.h>

// PopulationODE: sequential RK4 scan, T=4096, state=4, HID=32.
// One wave64, all state + weights in registers, ZERO LDS ops:
// cross-lane via DPP row_ror + v_permlane16/32_swap_b32 (VALU only).
//
// Lane map (rows of 16 lanes, m = lane>>4, i = lane&15):
//   vectors live in "ABAB" layout: row m holds v[16*(m&1) + i]
//   matvec: lane accumulates output row r_w = 16*(lane>>5)+i over
//           col block h_w = (lane>>4)&1 (the block its row holds locally)

__device__ __forceinline__ float fexp2(float x) { return __builtin_amdgcn_exp2f(x); }
__device__ __forceinline__ float frcp(float x) { return __builtin_amdgcn_rcpf(x); }
__device__ __forceinline__ float ftanh(float a) {
  float e = fexp2(a * 2.8853900817779268f);
  return 1.0f - 2.0f * frcp(e + 1.0f);
}
__device__ __forceinline__ float fsigm(float a) {
  float e = fexp2(a * -1.4426950408889634f);
  return frcp(1.0f + e);
}

template<int CTRL>
__device__ __forceinline__ float dppmov(float x) {
  return __int_as_float(__builtin_amdgcn_update_dpp(
      __float_as_int(x), __float_as_int(x), CTRL, 0xF, 0xF, false));
}
#define ROR1 0x121
#define ROR2 0x122
#define ROR4 0x124
#define ROR8 0x128

__device__ __forceinline__ void p16swap(float& a, float& b) {
  asm("v_permlane16_swap_b32 %0, %1" : "+v"(a), "+v"(b));
}
__device__ __forceinline__ void p32swap(float& a, float& b) {
  asm("v_permlane32_swap_b32 %0, %1" : "+v"(a), "+v"(b));
}

__global__ __launch_bounds__(64)
void ode_kernel(const float* __restrict__ s_grid,
                const float* __restrict__ y0in,
                const float* __restrict__ Win,
                const float* __restrict__ bin_,
                const float* __restrict__ W1a, const float* __restrict__ b1a,
                const float* __restrict__ W1b, const float* __restrict__ b1b,
                const float* __restrict__ W2a, const float* __restrict__ b2a,
                const float* __restrict__ W2b, const float* __restrict__ b2b,
                const float* __restrict__ Wout, const float* __restrict__ bout,
                const float* __restrict__ Aarr,
                float* __restrict__ out, int T) {
  const int lane = threadIdx.x;        // 0..63
  const int i = lane & 15;             // lane-in-row
  const int rowpar = (lane >> 4) & 1;  // which 16-col block this row holds
  const int rhi = lane >> 5;           // output-row half for matvec
  const int r_w = rhi * 16 + i;        // matvec output row owned by lane
  const int h_w = rowpar;              // matvec col block owned by lane
  const int r_in = rowpar * 16 + i;    // input-layer row (ABAB layout direct)

  // ---- one-time direction probes (DPP/permlane semantics agnostic) ----
  int delta;
  {
    float pr = (float)i;
    float pr1 = dppmov<ROR1>(pr);
    delta = (((int)pr1) - i) & 15;     // hw rotate step: +1 or 15(=-1)
  }
  bool p32_c_low;
  {
    float v = (float)(lane >> 5);
    float c = v, d = v;
    p32swap(c, d);
    p32_c_low = (c == 0.0f);           // c holds low-32 duplicate?
  }
  bool p16_case1;
  {
    float v = (float)(lane >> 4);
    float a = v, b = v;
    p16swap(a, b);
    p16_case1 = (a == (float)((lane >> 4) & ~1)); // a keeps even rows?
  }

  // ---- load constants into registers ----
  float w1a[16], w1b[16], w2a[16], w2b[16];
#pragma unroll
  for (int m = 0; m < 16; ++m) {
    int c = h_w * 16 + ((i + delta * m) & 15);   // col visited at rot step m
    w1a[m] = W1a[r_w * 32 + c];
    w1b[m] = W1b[r_w * 32 + c];
    w2a[m] = W2a[r_w * 32 + c];
    w2b[m] = W2b[r_w * 32 + c];
  }
  float winy0 = Win[r_in * 5 + 0], winy1 = Win[r_in * 5 + 1];
  float winy2 = Win[r_in * 5 + 2], winy3 = Win[r_in * 5 + 3];
  float wins = Win[r_in * 5 + 4];
  float binr = bin_[r_in];
  float bz1a = h_w ? 0.0f : b1a[r_w];
  float bz1b = h_w ? 0.0f : b1b[r_w];
  float bz2a = h_w ? 0.0f : b2a[r_w];
  float bz2b = h_w ? 0.0f : b2b[r_w];

  // head: lanes of half rhi handle Wout rows {2*rhi, 2*rhi+1}, cols 16*rowpar+i
  float woA = Wout[(2 * rhi + 0) * 32 + 16 * rowpar + i];
  float woB = Wout[(2 * rhi + 1) * 32 + 16 * rowpar + i];
  float bo0 = bout[0], bo1 = bout[1], bo2 = bout[2], bo3 = bout[3];
  float A0 = Aarr[0], A1 = Aarr[1], A2 = Aarr[2], A3 = Aarr[3];

  // ---- helpers ----
  // 32x32 matvec: x in ABAB layout -> result in AABB (dup) layout
  auto matvec = [&](const float (&w)[16], float bz, float xin) -> float {
    float x0 = xin;
    float x1 = dppmov<ROR1>(x0);
    float x2 = dppmov<ROR2>(x0);
    float x3 = dppmov<ROR2>(x1);
    float a0 = fmaf(w[0], x0, bz);
    float a1 = w[1] * x1;
    float a2 = w[2] * x2;
    float a3 = w[3] * x3;
#pragma unroll
    for (int j = 1; j < 4; ++j) {
      x0 = dppmov<ROR4>(x0);
      x1 = dppmov<ROR4>(x1);
      x2 = dppmov<ROR4>(x2);
      x3 = dppmov<ROR4>(x3);
      a0 = fmaf(w[4 * j + 0], x0, a0);
      a1 = fmaf(w[4 * j + 1], x1, a1);
      a2 = fmaf(w[4 * j + 2], x2, a2);
      a3 = fmaf(w[4 * j + 3], x3, a3);
    }
    float s = (a0 + a1) + (a2 + a3);
    float b = s;
    p16swap(s, b);        // exchange complementary 16-rows (dir-agnostic)
    return s + b;         // rows: [y0-15, y0-15, y16-31, y16-31]
  };

  // AABB (dup) -> ABAB layout
  auto relayout = [&](float v) -> float {
    float c = v, d = v;
    p32swap(c, d);                       // one is all-low-dup, one all-high
    float lo = p32_c_low ? c : d;
    float hi = p32_c_low ? d : c;
    float s0 = p16_case1 ? lo : hi;
    float s1 = p16_case1 ? hi : lo;
    p16swap(s0, s1);
    return s0;                           // [A,B,A,B]
  };

  auto feval = [&](float YA, float YB, float YC, float YD, float SV,
                   float& K0, float& K1, float& K2, float& K3) {
    float z = fmaf(winy0, YA, binr);
    z = fmaf(winy1, YB, z);
    z = fmaf(winy2, YC, z);
    z = fmaf(winy3, YD, z);
    z = fmaf(wins, SV, z);
    float x = ftanh(z);                          // ABAB
    float u1 = matvec(w1a, bz1a, x);             // AABB
    float t1 = relayout(ftanh(u1));              // ABAB
    float v1 = relayout(matvec(w1b, bz1b, t1));
    float x2 = x + v1;
    float u2 = matvec(w2a, bz2a, x2);
    float t2 = relayout(ftanh(u2));
    float v2 = relayout(matvec(w2b, bz2b, t2));
    float x3 = x2 + v2;
    // ---- output head: p0 -> Wout row 2*rhi, p1 -> row 2*rhi+1 ----
    float p0 = woA * x3;
    float p1 = woB * x3;
    p0 += dppmov<ROR8>(p0); p1 += dppmov<ROR8>(p1);
    p0 += dppmov<ROR4>(p0); p1 += dppmov<ROR4>(p1);
    p0 += dppmov<ROR2>(p0); p1 += dppmov<ROR2>(p1);
    p0 += dppmov<ROR1>(p0); p1 += dppmov<ROR1>(p1);   // row-local sums
    float q0 = p0; p16swap(p0, q0); p0 += q0;  // lanes0-31:P0, lanes32-63:P2
    float q1 = p1; p16swap(p1, q1); p1 += q1;  // lanes0-31:P1, lanes32-63:P3
    float c0 = p0, d0 = p0; p32swap(c0, d0);
    float P0 = p32_c_low ? c0 : d0;
    float P2 = p32_c_low ? d0 : c0;
    float c1 = p1, d1 = p1; p32swap(c1, d1);
    float P1 = p32_c_low ? c1 : d1;
    float P3 = p32_c_low ? d1 : c1;
    float n0 = fsigm(P0 + bo0), n1 = fsigm(P1 + bo1);
    float n2 = fsigm(P2 + bo2), n3 = fsigm(P3 + bo3);
    float s0 = fsigm(YA), s1 = fsigm(YB), s2 = fsigm(YC), s3 = fsigm(YD);
    K0 = 0.01f * s0 * (A0 - s0) * n0;
    K1 = 0.01f * s1 * (A1 - s1) * n1;
    K2 = 0.01f * s2 * (A2 - s2) * n2;
    K3 = 0.01f * s3 * (A3 - s3) * n3;
  };

  // ---- state (uniform across lanes) ----
  float y0v = y0in[0], y1v = y0in[1], y2v = y0in[2], y3v = y0in[3];

  if (lane < 4) {
    float ov = (lane == 0) ? y0v : (lane == 1) ? y1v : (lane == 2) ? y2v : y3v;
    out[lane] = ov;
  }

  float sp = s_grid[0];
  float sn = s_grid[1];

  for (int t = 0; t < T - 1; ++t) {
    float snn = s_grid[(t + 2 < T) ? (t + 2) : (T - 1)];  // prefetch
    float h = sn - sp;

    float k10, k11, k12, k13, k20, k21, k22, k23;
    float k30, k31, k32, k33, k40, k41, k42, k43;

    feval(y0v, y1v, y2v, y3v, sp, k10, k11, k12, k13);

    float hh = 0.5f * h;
    float ya0 = fmaf(hh, k10, y0v), ya1 = fmaf(hh, k11, y1v);
    float ya2 = fmaf(hh, k12, y2v), ya3 = fmaf(hh, k13, y3v);
    feval(ya0, ya1, ya2, ya3, sp, k20, k21, k22, k23);

    float yb0 = fmaf(hh, k20, y0v), yb1 = fmaf(hh, k21, y1v);
    float yb2 = fmaf(hh, k22, y2v), yb3 = fmaf(hh, k23, y3v);
    feval(yb0, yb1, yb2, yb3, sp, k30, k31, k32, k33);

    float yc0 = fmaf(h, k30, y0v), yc1 = fmaf(h, k31, y1v);
    float yc2 = fmaf(h, k32, y2v), yc3 = fmaf(h, k33, y3v);
    feval(yc0, yc1, yc2, yc3, sp, k40, k41, k42, k43);

    float h6 = h * (1.0f / 6.0f);
    y0v = fmaf(h6, k10 + k40 + 2.0f * (k20 + k30), y0v);
    y1v = fmaf(h6, k11 + k41 + 2.0f * (k21 + k31), y1v);
    y2v = fmaf(h6, k12 + k42 + 2.0f * (k22 + k32), y2v);
    y3v = fmaf(h6, k13 + k43 + 2.0f * (k23 + k33), y3v);

    if (lane < 4) {
      float ov = (lane == 0) ? y0v : (lane == 1) ? y1v : (lane == 2) ? y2v : y3v;
      out[(size_t)(t + 1) * 4 + lane] = ov;
    }

    sp = sn;
    sn = snn;
  }
}

extern "C" void kernel_launch(void* const* d_in, const int* in_sizes, int n_in,
                              void* d_out, int out_size, void* d_ws, size_t ws_size,
                              hipStream_t stream) {
  const float* s_grid = (const float*)d_in[0];
  const float* y0 = (const float*)d_in[1];
  const float* Win = (const float*)d_in[2];
  const float* bin_ = (const float*)d_in[3];
  const float* W1a = (const float*)d_in[4];
  const float* b1a = (const float*)d_in[5];
  const float* W1b = (const float*)d_in[6];
  const float* b1b = (const float*)d_in[7];
  const float* W2a = (const float*)d_in[8];
  const float* b2a = (const float*)d_in[9];
  const float* W2b = (const float*)d_in[10];
  const float* b2b = (const float*)d_in[11];
  const float* Wout = (const float*)d_in[12];
  const float* bout = (const float*)d_in[13];
  const float* A = (const float*)d_in[14];
  int T = in_sizes[0];

  ode_kernel<<<1, 64, 0, stream>>>(s_grid, y0, Win, bin_, W1a, b1a, W1b, b1b,
                                   W2a, b2a, W2b, b2b, Wout, bout, A,
                                   (float*)d_out, T);
}

// Round 3
// 7994.268 us; speedup vs baseline: 2.0917x; 1.3066x over previous
//
#include <hip/hip_runtime.h>

// PopulationODE: sequential RK4 scan, T=4096, state=4, HID=32.
// One wave64, all weights + state in VGPRs (waves_per_eu(1) -> no spill),
// zero LDS, zero scratch. Cross-lane via DPP row_ror (fusable into fmac)
// and v_permlane16/32_swap_b32.
//
// Layouts (m = lane>>4 row, i = lane&15):
//   ABAB: lane holds v[16*(m&1) + i]
//   AABB: lane holds v[16*(m>>1) + i]
// matvec_A: ABAB -> AABB (combine rows m^1 via p16swap)
// matvec_B: AABB -> ABAB (combine rows m^2 via p32swap)

__device__ __forceinline__ float fexp2(float x) { return __builtin_amdgcn_exp2f(x); }
__device__ __forceinline__ float frcp(float x) { return __builtin_amdgcn_rcpf(x); }
__device__ __forceinline__ float ftanh(float a) {
  float e = fexp2(a * 2.8853900817779268f);
  return 1.0f - 2.0f * frcp(e + 1.0f);
}
__device__ __forceinline__ float fsigm(float a) {
  float e = fexp2(a * -1.4426950408889634f);
  return frcp(1.0f + e);
}

// mov_dpp with bound_ctrl=1, full masks: canonical fusable form.
template<int CTRL>
__device__ __forceinline__ float dppmov(float x) {
  return __int_as_float(__builtin_amdgcn_update_dpp(
      0, __float_as_int(x), CTRL, 0xF, 0xF, true));
}
#define RORc(K) (0x120 | (K))

__device__ __forceinline__ void p16swap(float& a, float& b) {
  asm("v_permlane16_swap_b32 %0, %1" : "+v"(a), "+v"(b));
}
__device__ __forceinline__ void p32swap(float& a, float& b) {
  asm("v_permlane32_swap_b32 %0, %1" : "+v"(a), "+v"(b));
}

// 16 MACs: stream j handles rotation steps {j, j+4, j+8, j+12} from base.
// Bit-identical to round-2 arrangement (same pairing, same accumulation
// order, same (a0+a1)+(a2+a3) tree).
#define MV_CORE(W, BZ, X, SOUT) do {                                   \
    float a0_ = fmaf((X),                 W[0],  (BZ));                \
    float a1_ = dppmov<RORc(1)>(X)      * W[1];                        \
    float a2_ = dppmov<RORc(2)>(X)      * W[2];                        \
    float a3_ = dppmov<RORc(3)>(X)      * W[3];                        \
    a0_ = fmaf(dppmov<RORc(4)>(X),  W[4],  a0_);                       \
    a1_ = fmaf(dppmov<RORc(5)>(X),  W[5],  a1_);                       \
    a2_ = fmaf(dppmov<RORc(6)>(X),  W[6],  a2_);                       \
    a3_ = fmaf(dppmov<RORc(7)>(X),  W[7],  a3_);                       \
    a0_ = fmaf(dppmov<RORc(8)>(X),  W[8],  a0_);                       \
    a1_ = fmaf(dppmov<RORc(9)>(X),  W[9],  a1_);                       \
    a2_ = fmaf(dppmov<RORc(10)>(X), W[10], a2_);                       \
    a3_ = fmaf(dppmov<RORc(11)>(X), W[11], a3_);                       \
    a0_ = fmaf(dppmov<RORc(12)>(X), W[12], a0_);                       \
    a1_ = fmaf(dppmov<RORc(13)>(X), W[13], a1_);                       \
    a2_ = fmaf(dppmov<RORc(14)>(X), W[14], a2_);                       \
    a3_ = fmaf(dppmov<RORc(15)>(X), W[15], a3_);                       \
    SOUT = (a0_ + a1_) + (a2_ + a3_);                                  \
  } while (0)

__global__ __launch_bounds__(64, 1) __attribute__((amdgpu_waves_per_eu(1)))
void ode_kernel(const float* __restrict__ s_grid,
                const float* __restrict__ y0in,
                const float* __restrict__ Win,
                const float* __restrict__ bin_,
                const float* __restrict__ W1a, const float* __restrict__ b1a,
                const float* __restrict__ W1b, const float* __restrict__ b1b,
                const float* __restrict__ W2a, const float* __restrict__ b2a,
                const float* __restrict__ W2b, const float* __restrict__ b2b,
                const float* __restrict__ Wout, const float* __restrict__ bout,
                const float* __restrict__ Aarr,
                float* __restrict__ out, int T) {
  const int lane = threadIdx.x;   // 0..63
  const int i = lane & 15;
  const int m = lane >> 4;        // row 0..3
  const int mlo = m & 1;          // ABAB block / matvec_A col-block
  const int mhi = m >> 1;         // AABB block / matvec_B col-block

  // ---- one-time direction probes ----
  int delta;
  {
    float pr = (float)i;
    float pr1 = dppmov<RORc(1)>(pr);
    delta = (((int)pr1) - i) & 15;
  }
  bool p32_c_low;
  {
    float v = (float)(lane >> 5);
    float c = v, d = v;
    p32swap(c, d);
    p32_c_low = (c == 0.0f);
  }

  // ---- weights into registers ----
  // matvec_A (input ABAB): out row rA = 16*mhi + i, col block hA = mlo
  // matvec_B (input AABB): out row rB = 16*mlo + i, col block hB = mhi
  const int rA = 16 * mhi + i, hA = mlo;
  const int rB = 16 * mlo + i, hB = mhi;
  float w1a[16], w1b[16], w2a[16], w2b[16];
#pragma unroll
  for (int k = 0; k < 16; ++k) {
    int cA = hA * 16 + ((i + delta * k) & 15);
    int cB = hB * 16 + ((i + delta * k) & 15);
    w1a[k] = W1a[rA * 32 + cA];
    w2a[k] = W2a[rA * 32 + cA];
    w1b[k] = W1b[rB * 32 + cB];
    w2b[k] = W2b[rB * 32 + cB];
  }
  const int r_in = 16 * mlo + i;   // input layer produces ABAB
  float winy0 = Win[r_in * 5 + 0], winy1 = Win[r_in * 5 + 1];
  float winy2 = Win[r_in * 5 + 2], winy3 = Win[r_in * 5 + 3];
  float wins = Win[r_in * 5 + 4];
  float binr = bin_[r_in];
  float bz1a = hA ? 0.0f : b1a[rA];
  float bz2a = hA ? 0.0f : b2a[rA];
  float bz1b = hB ? 0.0f : b1b[rB];
  float bz2b = hB ? 0.0f : b2b[rB];

  // head: row m handles Wout rows {2*mhi, 2*mhi+1} over col block mlo
  float woA = Wout[(2 * mhi + 0) * 32 + 16 * mlo + i];
  float woB = Wout[(2 * mhi + 1) * 32 + 16 * mlo + i];
  // this lane's row-group components: (a,b) = (0,1) for rows 0,1; (2,3) rows 2,3
  float boa = mhi ? bout[2] : bout[0];
  float bob = mhi ? bout[3] : bout[1];
  float Aa = mhi ? Aarr[2] : Aarr[0];
  float Ab = mhi ? Aarr[3] : Aarr[1];
  const bool selhi = (mhi != 0);

  auto matvecA = [&](const float (&w)[16], float bz, float xin) -> float {
    float s;
    MV_CORE(w, bz, xin, s);
    float b = s;
    p16swap(s, b);
    return s + b;                  // AABB
  };
  auto matvecB = [&](const float (&w)[16], float bz, float xin) -> float {
    float s;
    MV_CORE(w, bz, xin, s);
    float b = s;
    p32swap(s, b);
    return s + b;                  // ABAB
  };

  auto feval = [&](float YA, float YB, float YC, float YD, float SV,
                   float& K0, float& K1, float& K2, float& K3) {
    // off-critical-path: prefactors for this lane's two components
    float Ya = selhi ? YC : YA;
    float Yb = selhi ? YD : YB;
    float s_a = fsigm(Ya), s_b = fsigm(Yb);
    float pref_a = 0.01f * s_a * (Aa - s_a);
    float pref_b = 0.01f * s_b * (Ab - s_b);
    // critical path
    float z = fmaf(winy0, YA, binr);
    z = fmaf(winy1, YB, z);
    z = fmaf(winy2, YC, z);
    z = fmaf(winy3, YD, z);
    z = fmaf(wins, SV, z);
    float x = ftanh(z);                       // ABAB
    float u1 = matvecA(w1a, bz1a, x);         // AABB
    float t1 = ftanh(u1);
    float v1 = matvecB(w1b, bz1b, t1);        // ABAB
    float x2 = x + v1;
    float u2 = matvecA(w2a, bz2a, x2);        // AABB
    float t2 = ftanh(u2);
    float v2 = matvecB(w2b, bz2b, t2);        // ABAB
    float x3 = x2 + v2;
    // head
    float p0 = woA * x3;
    float p1 = woB * x3;
    p0 += dppmov<RORc(8)>(p0); p1 += dppmov<RORc(8)>(p1);
    p0 += dppmov<RORc(4)>(p0); p1 += dppmov<RORc(4)>(p1);
    p0 += dppmov<RORc(2)>(p0); p1 += dppmov<RORc(2)>(p1);
    p0 += dppmov<RORc(1)>(p0); p1 += dppmov<RORc(1)>(p1);
    float q0 = p0; p16swap(p0, q0); p0 += q0;  // rows0,1:P0  rows2,3:P2
    float q1 = p1; p16swap(p1, q1); p1 += q1;  // rows0,1:P1  rows2,3:P3
    float n_a = fsigm(p0 + boa);
    float n_b = fsigm(p1 + bob);
    float Ka = pref_a * n_a;     // rows0,1: K0   rows2,3: K2
    float Kb = pref_b * n_b;     // rows0,1: K1   rows2,3: K3
    float c0 = Ka, d0 = Ka; p32swap(c0, d0);
    K0 = p32_c_low ? c0 : d0;
    K2 = p32_c_low ? d0 : c0;
    float c1 = Kb, d1 = Kb; p32swap(c1, d1);
    K1 = p32_c_low ? c1 : d1;
    K3 = p32_c_low ? d1 : c1;
  };

  // ---- state ----
  float y0v = y0in[0], y1v = y0in[1], y2v = y0in[2], y3v = y0in[3];

  if (lane < 4) {
    float ov = (lane == 0) ? y0v : (lane == 1) ? y1v : (lane == 2) ? y2v : y3v;
    out[lane] = ov;
  }

  float sp = s_grid[0];
  float sn = s_grid[1];

  for (int t = 0; t < T - 1; ++t) {
    float snn = s_grid[(t + 2 < T) ? (t + 2) : (T - 1)];  // prefetch
    float h = sn - sp;

    float k10, k11, k12, k13, k20, k21, k22, k23;
    float k30, k31, k32, k33, k40, k41, k42, k43;

    feval(y0v, y1v, y2v, y3v, sp, k10, k11, k12, k13);

    float hh = 0.5f * h;
    float ya0 = fmaf(hh, k10, y0v), ya1 = fmaf(hh, k11, y1v);
    float ya2 = fmaf(hh, k12, y2v), ya3 = fmaf(hh, k13, y3v);
    feval(ya0, ya1, ya2, ya3, sp, k20, k21, k22, k23);

    float yb0 = fmaf(hh, k20, y0v), yb1 = fmaf(hh, k21, y1v);
    float yb2 = fmaf(hh, k22, y2v), yb3 = fmaf(hh, k23, y3v);
    feval(yb0, yb1, yb2, yb3, sp, k30, k31, k32, k33);

    float yc0 = fmaf(h, k30, y0v), yc1 = fmaf(h, k31, y1v);
    float yc2 = fmaf(h, k32, y2v), yc3 = fmaf(h, k33, y3v);
    feval(yc0, yc1, yc2, yc3, sp, k40, k41, k42, k43);

    float h6 = h * (1.0f / 6.0f);
    y0v = fmaf(h6, k10 + k40 + 2.0f * (k20 + k30), y0v);
    y1v = fmaf(h6, k11 + k41 + 2.0f * (k21 + k31), y1v);
    y2v = fmaf(h6, k12 + k42 + 2.0f * (k22 + k32), y2v);
    y3v = fmaf(h6, k13 + k43 + 2.0f * (k23 + k33), y3v);

    if (lane < 4) {
      float ov = (lane == 0) ? y0v : (lane == 1) ? y1v : (lane == 2) ? y2v : y3v;
      out[(size_t)(t + 1) * 4 + lane] = ov;
    }

    sp = sn;
    sn = snn;
  }
}

extern "C" void kernel_launch(void* const* d_in, const int* in_sizes, int n_in,
                              void* d_out, int out_size, void* d_ws, size_t ws_size,
                              hipStream_t stream) {
  const float* s_grid = (const float*)d_in[0];
  const float* y0 = (const float*)d_in[1];
  const float* Win = (const float*)d_in[2];
  const float* bin_ = (const float*)d_in[3];
  const float* W1a = (const float*)d_in[4];
  const float* b1a = (const float*)d_in[5];
  const float* W1b = (const float*)d_in[6];
  const float* b1b = (const float*)d_in[7];
  const float* W2a = (const float*)d_in[8];
  const float* b2a = (const float*)d_in[9];
  const float* W2b = (const float*)d_in[10];
  const float* b2b = (const float*)d_in[11];
  const float* Wout = (const float*)d_in[12];
  const float* bout = (const float*)d_in[13];
  const float* A = (const float*)d_in[14];
  int T = in_sizes[0];

  ode_kernel<<<1, 64, 0, stream>>>(s_grid, y0, Win, bin_, W1a, b1a, W1b, b1b,
                                   W2a, b2a, W2b, b2b, Wout, bout, A,
                                   (float*)d_out, T);
}